// Round 5
// baseline (1194.627 us; speedup 1.0000x reference)
//
#include <hip/hip_runtime.h>
#include <math.h>

// ComplexPolarTransformerBeta — round 5: MFMA bf16 hi/lo split-3, spill fix.
// Changes vs R4: __launch_bounds__(512,1) (R4's (512,2) capped VGPRs at 128 ->
// 730 MB scratch spill traffic = the whole runtime); vm GEMM deferred until
// after attn staging so accVM doesn't live across Q/K/scores (peak acc pressure
// 96 -> 64 floats). LDS pins 1 block/CU anyway, so 256 VGPRs are free.

typedef __attribute__((ext_vector_type(8)))  short s16x8;
typedef __attribute__((ext_vector_type(16))) float f32x16;

#define STR  136      // LDS row stride (shorts / floats): 128 data + 8 pad
#define LOFS 17408    // offset of lo-array within a region (128*136 shorts)
#define MFMA(a, b, c) __builtin_amdgcn_mfma_f32_32x32x16_bf16(a, b, c, 0, 0, 0)
#define ROWP(reg) (((reg) & 3) + (((reg) >> 2) << 3) + (h5 << 2))

__device__ __forceinline__ unsigned short bfhi(float x) {
  unsigned u = __float_as_uint(x);
  return (unsigned short)((u + 0x7FFFu + ((u >> 16) & 1u)) >> 16);
}
__device__ __forceinline__ float bf2f(unsigned short h) {
  return __uint_as_float(((unsigned)h) << 16);
}

// Stage C-layout acc into S[row=n][col=m] bf16 hi/lo (packed b64 over reg-quads).
__device__ __forceinline__ void stageB64(short* SH, const f32x16 acc[2],
                                         int nb0, int l31, int h5, int mblk, float scl) {
  #pragma unroll
  for (int tl = 0; tl < 2; ++tl) {
    int row = nb0 + 32 * tl + l31;
    #pragma unroll
    for (int q = 0; q < 4; ++q) {
      int col = mblk + 8 * q + 4 * h5;
      float v0 = acc[tl][4*q+0] * scl, v1 = acc[tl][4*q+1] * scl;
      float v2 = acc[tl][4*q+2] * scl, v3 = acc[tl][4*q+3] * scl;
      unsigned short h0 = bfhi(v0), h1 = bfhi(v1), h2 = bfhi(v2), h3 = bfhi(v3);
      short4 hv = make_short4((short)h0, (short)h1, (short)h2, (short)h3);
      short4 lv = make_short4((short)bfhi(v0 - bf2f(h0)), (short)bfhi(v1 - bf2f(h1)),
                              (short)bfhi(v2 - bf2f(h2)), (short)bfhi(v3 - bf2f(h3)));
      *(short4*)(SH + row * STR + col) = hv;
      *(short4*)(SH + LOFS + row * STR + col) = lv;
    }
  }
}

// Stage per-thread state v[32] (C-layout) into S[a][h] bf16 hi/lo.
__device__ __forceinline__ void stageScatter(short* SH, const float* v,
                                             int nb0, int l31, int h5, int mblk) {
  #pragma unroll
  for (int tl = 0; tl < 2; ++tl) {
    int col = nb0 + 32 * tl + l31;
    #pragma unroll
    for (int reg = 0; reg < 16; ++reg) {
      int row = mblk + ROWP(reg);
      float x = v[tl * 16 + reg];
      unsigned short h = bfhi(x);
      SH[row * STR + col] = (short)h;
      SH[LOFS + row * STR + col] = (short)bfhi(x - bf2f(h));
    }
  }
}

// D[m][n] += A(LDS)[m][k] * B(LDS)^T[k][n]  (both [row][k-contig] bf16 hi/lo)
__device__ __forceinline__ void gemmLL(f32x16 acc[2], const short* AH, const short* BH,
                                       int mblk, int nb0, int l31, int h5) {
  int arow = mblk + l31;
  #pragma unroll
  for (int kb = 0; kb < 8; ++kb) {
    int k0 = kb * 16 + 8 * h5;
    s16x8 ah = *(const s16x8*)(AH + arow * STR + k0);
    s16x8 al = *(const s16x8*)(AH + LOFS + arow * STR + k0);
    #pragma unroll
    for (int tl = 0; tl < 2; ++tl) {
      int brow = nb0 + 32 * tl + l31;
      s16x8 bh = *(const s16x8*)(BH + brow * STR + k0);
      s16x8 bl = *(const s16x8*)(BH + LOFS + brow * STR + k0);
      acc[tl] = MFMA(ah, bh, acc[tl]);
      acc[tl] = MFMA(ah, bl, acc[tl]);
      acc[tl] = MFMA(al, bh, acc[tl]);
    }
  }
}

// D[m=a][n=h]: A = LDS activation rows, B = preprocessed weight (frag-ordered).
__device__ __forceinline__ void gemmNW(f32x16 acc[2], const short* AH, const short* W,
                                       int mblk, int w1, int l31, int h5, int lane) {
  int arow = mblk + l31;
  #pragma unroll
  for (int kb = 0; kb < 8; ++kb) {
    int k0 = kb * 16 + 8 * h5;
    s16x8 ah = *(const s16x8*)(AH + arow * STR + k0);
    s16x8 al = *(const s16x8*)(AH + LOFS + arow * STR + k0);
    #pragma unroll
    for (int tl = 0; tl < 2; ++tl) {
      int hblk = 2 * w1 + tl;
      const short* wp = W + (((hblk * 8 + kb) * 64 + lane) * 8);
      s16x8 bh = *(const s16x8*)wp;
      s16x8 bl = *(const s16x8*)(wp + 32768);
      acc[tl] = MFMA(ah, bh, acc[tl]);
      acc[tl] = MFMA(ah, bl, acc[tl]);
      acc[tl] = MFMA(al, bh, acc[tl]);
    }
  }
}

// D[m=h][n=i]: A = preprocessed weight (m-tile = w>>1), B = LDS activation rows.
__device__ __forceinline__ void gemmTW(f32x16 acc[2], const short* W, const short* BH,
                                       int mt, int nb0, int l31, int h5, int lane) {
  #pragma unroll
  for (int kb = 0; kb < 8; ++kb) {
    int k0 = kb * 16 + 8 * h5;
    const short* wp = W + (((mt * 8 + kb) * 64 + lane) * 8);
    s16x8 ah = *(const s16x8*)wp;
    s16x8 al = *(const s16x8*)(wp + 32768);
    #pragma unroll
    for (int tl = 0; tl < 2; ++tl) {
      int brow = nb0 + 32 * tl + l31;
      s16x8 bh = *(const s16x8*)(BH + brow * STR + k0);
      s16x8 bl = *(const s16x8*)(BH + LOFS + brow * STR + k0);
      acc[tl] = MFMA(ah, bh, acc[tl]);
      acc[tl] = MFMA(ah, bl, acc[tl]);
      acc[tl] = MFMA(al, bh, acc[tl]);
    }
  }
}

// ---------------- weight preprocessing ----------------
__global__ __launch_bounds__(512)
void prep_kernel(const float* __restrict__ Wq, const float* __restrict__ Wk,
                 const float* __restrict__ Wvm, const float* __restrict__ Wvp,
                 const float* __restrict__ rp_W, short* __restrict__ ws) {
  int mid = blockIdx.x >> 2, hblk = blockIdx.x & 3;
  int kb = threadIdx.x >> 6, lane = threadIdx.x & 63;
  const float* src;
  if (mid < 4)       src = Wq  + mid * 16384;
  else if (mid < 8)  src = Wk  + (mid - 4) * 16384;
  else if (mid < 12) src = Wvm + (mid - 8) * 16384;
  else if (mid < 16) src = Wvp + (mid - 12) * 16384;
  else if (mid == 16) src = rp_W;
  else                src = rp_W + 16384;
  int h = hblk * 32 + (lane & 31);
  int kbase = kb * 16 + ((lane >> 5) << 3);
  s16x8 H, L;
  #pragma unroll
  for (int j = 0; j < 8; ++j) {
    float v = src[(size_t)(kbase + j) * 128 + h];
    unsigned short hi = bfhi(v);
    H[j] = (short)hi;
    L[j] = (short)bfhi(v - bf2f(hi));
  }
  short* dst = ws + (size_t)mid * 65536 + ((hblk * 8 + kb) * 64 + lane) * 8;
  *(s16x8*)dst = H;
  *(s16x8*)(dst + 32768) = L;
}

// ---------------- main kernel ----------------
__global__ __launch_bounds__(512, 1)
void cpt_kernel(const float* __restrict__ atom_types,
                const float* __restrict__ coords,
                const int*   __restrict__ edge_index,
                const float* __restrict__ edge_attr,
                const float* __restrict__ emb_Wm, const float* __restrict__ emb_bm,
                const float* __restrict__ emb_Wp, const float* __restrict__ emb_bp,
                const float* __restrict__ bq, const float* __restrict__ bk,
                const float* __restrict__ bvm, const float* __restrict__ bvp,
                const float* __restrict__ We,  const float* __restrict__ be,
                const float* __restrict__ dist_scale,
                const float* __restrict__ ln_g, const float* __restrict__ ln_b,
                const float* __restrict__ rp_b,
                const float* __restrict__ h1_W, const float* __restrict__ h1_b,
                const float* __restrict__ h2_W, const float* __restrict__ h2_b,
                const short* __restrict__ wpre,
                float* __restrict__ out)
{
  __shared__ __align__(16) short R1s[34816];
  __shared__ __align__(16) short R2s[34816];
  __shared__ float SCa[512];
  __shared__ float SCb[512];

  const int t = threadIdx.x, b = blockIdx.x;
  const int w = t >> 6, lane = t & 63, l31 = lane & 31, h5 = lane >> 5;
  const int mblk = (w >> 1) << 5;
  const int w1 = w & 1;
  const int nb0 = w1 << 6;
  const float scale = 0.08838834764831845f;  // 1/sqrt(128)

  // ---- edge gather (layer-invariant) ----
  int efA, efB; float4 eaA, eaB;
  {
    int e0 = t, e1 = t + 512;
    int i0 = edge_index[(size_t)b * 2048 + e0];
    int j0 = edge_index[(size_t)b * 2048 + 1024 + e0];
    int i1 = edge_index[(size_t)b * 2048 + e1];
    int j1 = edge_index[(size_t)b * 2048 + 1024 + e1];
    efA = i0 * STR + j0;  efB = i1 * STR + j1;
    eaA = *(const float4*)(edge_attr + ((size_t)b * 1024 + e0) * 4);
    eaB = *(const float4*)(edge_attr + ((size_t)b * 1024 + e1) * 4);
  }

  // ---- embedding -> magP/phP (C-layout) ----
  float magP[32], phP[32];
  {
    float wmv0[19], wpv0[19], wmv1[19], wpv1[19];
    int h0 = nb0 + l31, h1 = nb0 + 32 + l31;
    #pragma unroll
    for (int d = 0; d < 19; ++d) {
      wmv0[d] = emb_Wm[d * 128 + h0]; wpv0[d] = emb_Wp[d * 128 + h0];
      wmv1[d] = emb_Wm[d * 128 + h1]; wpv1[d] = emb_Wp[d * 128 + h1];
    }
    float bm0 = emb_bm[h0], bp0 = emb_bp[h0], bm1 = emb_bm[h1], bp1 = emb_bp[h1];
    #pragma unroll
    for (int reg = 0; reg < 16; ++reg) {
      int a = mblk + ROWP(reg);
      const float* xr = atom_types + ((size_t)b * 128 + a) * 16;
      float x[19];
      float4 v0 = *(const float4*)xr,      v1 = *(const float4*)(xr + 4);
      float4 v2 = *(const float4*)(xr + 8), v3 = *(const float4*)(xr + 12);
      x[0]=v0.x; x[1]=v0.y; x[2]=v0.z; x[3]=v0.w;
      x[4]=v1.x; x[5]=v1.y; x[6]=v1.z; x[7]=v1.w;
      x[8]=v2.x; x[9]=v2.y; x[10]=v2.z; x[11]=v2.w;
      x[12]=v3.x; x[13]=v3.y; x[14]=v3.z; x[15]=v3.w;
      const float* cr = coords + ((size_t)b * 128 + a) * 3;
      x[16]=cr[0]; x[17]=cr[1]; x[18]=cr[2];
      float m0 = bm0, p0 = bp0, m1 = bm1, p1 = bp1;
      #pragma unroll
      for (int d = 0; d < 19; ++d) {
        m0 += x[d] * wmv0[d]; p0 += x[d] * wpv0[d];
        m1 += x[d] * wmv1[d]; p1 += x[d] * wpv1[d];
      }
      magP[reg] = m0; phP[reg] = p0; magP[16 + reg] = m1; phP[16 + reg] = p1;
    }
  }

  // ---- layers ----
  for (int l = 0; l < 4; ++l) {
    const short* wqP  = wpre + (size_t)l * 65536;
    const short* wkP  = wpre + (size_t)(4 + l) * 65536;
    const short* wvmP = wpre + (size_t)(8 + l) * 65536;
    const short* wvpP = wpre + (size_t)(12 + l) * 65536;
    float we0 = We[l*4], we1 = We[l*4+1], we2 = We[l*4+2], we3 = We[l*4+3];
    float bel = be[l], dsl = dist_scale[l];

    __syncthreads();                       // prior readers of R1/R2 done
    float* biasF = (float*)R1s;            // fp32 [128][STR] bias matrix
    {
      float4* z4 = (float4*)R1s;
      #pragma unroll
      for (int k = 0; k < 9; ++k) { int idx = t + 512 * k; if (idx < 4352) z4[idx] = make_float4(0.f,0.f,0.f,0.f); }
    }
    __syncthreads();
    {
      float bvA = eaA.x*we0 + eaA.y*we1 + eaA.z*we2 + eaA.w*we3 + bel + dsl*eaA.x;
      float bvB = eaB.x*we0 + eaB.y*we1 + eaB.z*we2 + eaB.w*we3 + bel + dsl*eaB.x;
      atomicAdd(&biasF[efA], bvA);
      atomicAdd(&biasF[efB], bvB);
    }
    __syncthreads();
    // preload scores acc with bias (scoresT: m=j=mblk+ROWP, n=i=nb0+32tl+l31)
    f32x16 accS[2];
    #pragma unroll
    for (int tl = 0; tl < 2; ++tl) {
      int i = nb0 + 32 * tl + l31;
      #pragma unroll
      for (int reg = 0; reg < 16; ++reg)
        accS[tl][reg] = biasF[i * STR + (mblk + ROWP(reg))];
    }
    __syncthreads();                       // bias reads done
    stageScatter(R1s, magP, nb0, l31, h5, mblk);   // mag -> R1 [a][h]
    __syncthreads();

    // Q^T (D[h][i]) -> R2 scaled; then K^T (D[h][j])
    {
      f32x16 accQ[2];
      #pragma unroll
      for (int reg = 0; reg < 16; ++reg) {
        float bv = bq[l * 128 + mblk + ROWP(reg)];
        accQ[0][reg] = bv; accQ[1][reg] = bv;
      }
      gemmTW(accQ, wqP, R1s, w >> 1, nb0, l31, h5, lane);
      stageB64(R2s, accQ, nb0, l31, h5, mblk, scale);  // (scale*Q)[i][h] -> R2
    }
    f32x16 accK[2];
    {
      #pragma unroll
      for (int reg = 0; reg < 16; ++reg) {
        float bv = bk[l * 128 + mblk + ROWP(reg)];
        accK[0][reg] = bv; accK[1][reg] = bv;
      }
      gemmTW(accK, wkP, R1s, w >> 1, nb0, l31, h5, lane);
    }
    __syncthreads();                       // mag reads + Q writes done
    stageB64(R1s, accK, nb0, l31, h5, mblk, 1.0f);   // K[j][h] -> R1 (over mag)
    __syncthreads();

    // scoresT[j][i] = K @ (scale*Q)^T + bias
    gemmLL(accS, R1s, R2s, mblk, nb0, l31, h5);

    // softmax over j
    #pragma unroll
    for (int tl = 0; tl < 2; ++tl) {
      float m = accS[tl][0];
      #pragma unroll
      for (int reg = 1; reg < 16; ++reg) m = fmaxf(m, accS[tl][reg]);
      m = fmaxf(m, __shfl_xor(m, 32));
      if (h5 == 0) SCa[(w >> 1) * 128 + nb0 + 32 * tl + l31] = m;
    }
    __syncthreads();
    #pragma unroll
    for (int tl = 0; tl < 2; ++tl) {
      int i = nb0 + 32 * tl + l31;
      float mg = fmaxf(fmaxf(SCa[i], SCa[128 + i]), fmaxf(SCa[256 + i], SCa[384 + i]));
      float s = 0.f;
      #pragma unroll
      for (int reg = 0; reg < 16; ++reg) {
        float e = __expf(accS[tl][reg] - mg);
        accS[tl][reg] = e; s += e;
      }
      s += __shfl_xor(s, 32);
      if (h5 == 0) SCb[(w >> 1) * 128 + i] = s;
    }
    __syncthreads();
    #pragma unroll
    for (int tl = 0; tl < 2; ++tl) {
      int i = nb0 + 32 * tl + l31;
      float sg = SCb[i] + SCb[128 + i] + SCb[256 + i] + SCb[384 + i];
      float inv = 1.f / sg;
      #pragma unroll
      for (int reg = 0; reg < 16; ++reg) accS[tl][reg] *= inv;
    }
    __syncthreads();                       // scores reads of R1/R2 done
    stageB64(R2s, accS, nb0, l31, h5, mblk, 1.0f);   // attn[i][j] -> R2 (over Q)
    stageScatter(R1s, magP, nb0, l31, h5, mblk);     // mag -> R1 (over K)
    __syncthreads();

    // vm = mag @ Wvm (deferred: accVM not live across scores)
    {
      f32x16 accVM[2];
      #pragma unroll
      for (int tl = 0; tl < 2; ++tl) {
        float bv = bvm[l * 128 + nb0 + 32 * tl + l31];
        #pragma unroll
        for (int reg = 0; reg < 16; ++reg) accVM[tl][reg] = bv;
      }
      gemmNW(accVM, R1s, wvmP, mblk, w1, l31, h5, lane);
      __syncthreads();                     // mag reads done
      stageB64(R1s, accVM, nb0, l31, h5, mblk, 1.0f);  // vm[h][a] -> R1
      __syncthreads();
    }

    // new_mag = attn @ vm + mag
    f32x16 accM[2];
    #pragma unroll
    for (int tl = 0; tl < 2; ++tl)
      #pragma unroll
      for (int reg = 0; reg < 16; ++reg) accM[tl][reg] = magP[tl * 16 + reg];
    gemmLL(accM, R2s, R1s, mblk, nb0, l31, h5);

    // LayerNorm over h
    {
      float sv[16], qv[16];
      #pragma unroll
      for (int reg = 0; reg < 16; ++reg) {
        float a0 = accM[0][reg], a1 = accM[1][reg];
        float s = a0 + a1, q = a0 * a0 + a1 * a1;
        #pragma unroll
        for (int off = 1; off < 32; off <<= 1) { s += __shfl_xor(s, off); q += __shfl_xor(q, off); }
        sv[reg] = s; qv[reg] = q;
      }
      if (l31 == 0) {
        #pragma unroll
        for (int reg = 0; reg < 16; ++reg) {
          SCa[w * 32 + ROWP(reg)] = sv[reg];
          SCb[w * 32 + ROWP(reg)] = qv[reg];
        }
      }
      __syncthreads();
      float g0 = ln_g[l * 128 + nb0 + l31],      lb0 = ln_b[l * 128 + nb0 + l31];
      float g1 = ln_g[l * 128 + nb0 + 32 + l31], lb1 = ln_b[l * 128 + nb0 + 32 + l31];
      #pragma unroll
      for (int reg = 0; reg < 16; ++reg) {
        float s = sv[reg] + SCa[(w ^ 1) * 32 + ROWP(reg)];
        float q = qv[reg] + SCb[(w ^ 1) * 32 + ROWP(reg)];
        float mu = s * (1.f / 128.f);
        float var = q * (1.f / 128.f) - mu * mu;
        float inv = 1.f / sqrtf(var + 1e-5f);
        magP[reg]      = g0 * ((accM[0][reg] - mu) * inv) + lb0;
        magP[16 + reg] = g1 * ((accM[1][reg] - mu) * inv) + lb1;
      }
    }
    __syncthreads();                       // vm reads of R1 done
    stageScatter(R1s, phP, nb0, l31, h5, mblk);      // ph[a][h] -> R1
    __syncthreads();

    // vp = ph @ Wvp
    {
      f32x16 accV[2];
      #pragma unroll
      for (int tl = 0; tl < 2; ++tl) {
        float bv = bvp[l * 128 + nb0 + 32 * tl + l31];
        #pragma unroll
        for (int reg = 0; reg < 16; ++reg) accV[tl][reg] = bv;
      }
      gemmNW(accV, R1s, wvpP, mblk, w1, l31, h5, lane);
      __syncthreads();                     // ph reads done
      stageB64(R1s, accV, nb0, l31, h5, mblk, 1.0f); // vp[h][a] -> R1
      __syncthreads();
    }

    // new_ph = attn @ vp + ph
    f32x16 accP[2];
    #pragma unroll
    for (int tl = 0; tl < 2; ++tl)
      #pragma unroll
      for (int reg = 0; reg < 16; ++reg) accP[tl][reg] = phP[tl * 16 + reg];
    gemmLL(accP, R2s, R1s, mblk, nb0, l31, h5);
    #pragma unroll
    for (int tl = 0; tl < 2; ++tl)
      #pragma unroll
      for (int reg = 0; reg < 16; ++reg) phP[tl * 16 + reg] = accP[tl][reg];
  } // layers

  // ---- real/imag -> RealProjection ----
  float reB[32], imB[32];
  #pragma unroll
  for (int i = 0; i < 32; ++i) {
    float s_, c_;
    __sincosf(phP[i], &s_, &c_);
    reB[i] = magP[i] * c_;
    imB[i] = magP[i] * s_;
  }
  __syncthreads();
  stageScatter(R1s, reB, nb0, l31, h5, mblk);
  stageScatter(R2s, imB, nb0, l31, h5, mblk);
  __syncthreads();
  f32x16 accR[2];
  #pragma unroll
  for (int tl = 0; tl < 2; ++tl) {
    float bv = rp_b[nb0 + 32 * tl + l31];
    #pragma unroll
    for (int reg = 0; reg < 16; ++reg) accR[tl][reg] = bv;
  }
  gemmNW(accR, R1s, wpre + (size_t)16 * 65536, mblk, w1, l31, h5, lane);  // real @ rpA
  gemmNW(accR, R2s, wpre + (size_t)17 * 65536, mblk, w1, l31, h5, lane);  // imag @ rpB

  // ---- pooling (column sum over atoms) ----
  #pragma unroll
  for (int tl = 0; tl < 2; ++tl) {
    float ps = 0.f;
    #pragma unroll
    for (int reg = 0; reg < 16; ++reg) ps += accR[tl][reg];
    ps += __shfl_xor(ps, 32);
    if (h5 == 0) SCa[(w >> 1) * 128 + nb0 + 32 * tl + l31] = ps;
  }
  __syncthreads();
  if (t < 128) {
    float cs = SCa[t] + SCa[128 + t] + SCa[256 + t] + SCa[384 + t];
    SCb[t] = cs;
  }
  __syncthreads();
  if (t < 128) {
    float acc = h1_b[t];
    for (int i = 0; i < 128; ++i) {
      float cs = SCb[i];
      acc += cs * (h1_W[(size_t)i * 128 + t] * (1.f / 128.f) +
                   h1_W[(size_t)(128 + i) * 128 + t]);
    }
    float hv = acc / (1.f + __expf(-acc));   // SiLU
    SCb[128 + t] = hv * h2_W[t];
  }
  __syncthreads();
  if (t < 64) {
    float s2 = SCb[128 + t] + SCb[192 + t];
    #pragma unroll
    for (int off = 32; off >= 1; off >>= 1) s2 += __shfl_xor(s2, off);
    if (t == 0) out[b] = s2 + h2_b[0];
  }
}

extern "C" void kernel_launch(void* const* d_in, const int* in_sizes, int n_in,
                              void* d_out, int out_size, void* d_ws, size_t ws_size,
                              hipStream_t stream) {
  const float* atom_types = (const float*)d_in[0];
  const float* coords     = (const float*)d_in[1];
  const int*   edge_index = (const int*)  d_in[2];
  const float* edge_attr  = (const float*)d_in[3];
  const float* emb_Wm = (const float*)d_in[4];
  const float* emb_bm = (const float*)d_in[5];
  const float* emb_Wp = (const float*)d_in[6];
  const float* emb_bp = (const float*)d_in[7];
  const float* Wq  = (const float*)d_in[8];
  const float* bq  = (const float*)d_in[9];
  const float* Wk  = (const float*)d_in[10];
  const float* bk  = (const float*)d_in[11];
  const float* Wvm = (const float*)d_in[12];
  const float* bvm = (const float*)d_in[13];
  const float* Wvp = (const float*)d_in[14];
  const float* bvp = (const float*)d_in[15];
  const float* We  = (const float*)d_in[16];
  const float* be  = (const float*)d_in[17];
  const float* dist_scale = (const float*)d_in[18];
  const float* ln_g = (const float*)d_in[19];
  const float* ln_b = (const float*)d_in[20];
  const float* rp_W = (const float*)d_in[21];
  const float* rp_b = (const float*)d_in[22];
  const float* h1_W = (const float*)d_in[23];
  const float* h1_b = (const float*)d_in[24];
  const float* h2_W = (const float*)d_in[25];
  const float* h2_b = (const float*)d_in[26];
  float* out = (float*)d_out;
  short* wpre = (short*)d_ws;   // 18 matrices * 65536 shorts = 2.36 MB

  hipLaunchKernelGGL(prep_kernel, dim3(72), dim3(512), 0, stream,
                     Wq, Wk, Wvm, Wvp, rp_W, wpre);
  hipLaunchKernelGGL(cpt_kernel, dim3(1024), dim3(512), 0, stream,
                     atom_types, coords, edge_index, edge_attr,
                     emb_Wm, emb_bm, emb_Wp, emb_bp,
                     bq, bk, bvm, bvp,
                     We, be, dist_scale, ln_g, ln_b,
                     rp_b, h1_W, h1_b, h2_W, h2_b,
                     (const short*)wpre, out);
}